// Round 1
// baseline (104359.229 us; speedup 1.0000x reference)
//
#include <hip/hip_runtime.h>
#include <math.h>

#define V_  128
#define E_  512
#define H_  1024
#define NE_ 10
#define B_  32
#define S_  1024
#define G4H (4*H_)   // 4096

// ---------------- K1: T[v][g] = sum_e emb[v][e]*W_ih[g][e] + b_ih[g] ----------------
__global__ __launch_bounds__(256) void build_T(
    const float* __restrict__ emb, const float* __restrict__ W_ih,
    const float* __restrict__ b_ih, float* __restrict__ T)
{
    int idx = blockIdx.x * 256 + threadIdx.x;    // over 4096*128
    int g = idx >> 7, v = idx & 127;
    const float* er = emb + v * E_;
    const float* wr = W_ih + (size_t)g * E_;
    float acc = b_ih[g];
    #pragma unroll 4
    for (int e = 0; e < E_; ++e) acc += er[e] * wr[e];
    T[v * G4H + g] = acc;
}

// ---------------- K2: persistent LSTM scan ----------------
// 256 blocks (one per CU), block p owns hidden units j = 4p..4p+3.
// W_hh rows for those units (16 rows x 1024) live in LDS for the whole scan.
__global__ __launch_bounds__(512) void lstm_scan(
    const int* __restrict__ x, const float* __restrict__ T,
    const float* __restrict__ W_hh, const float* __restrict__ b_hh,
    float* __restrict__ hbuf, float* __restrict__ h_all, int* __restrict__ bar)
{
    const int p   = blockIdx.x;      // 0..255
    const int tid = threadIdx.x;     // 0..511

    // local row r = u*4+q  (unit u in 0..3, gate q: 0=i,1=f,2=g,3=o), pad rows by 4 floats
    __shared__ float Wl[16][1028];
    __shared__ float pre_s[32][16];
    __shared__ float c_s[32][4];
    __shared__ float bhh_l[16];

    for (int idx = tid; idx < 16 * 1024; idx += 512) {
        int r = idx >> 10, k = idx & 1023;
        int u = r >> 2, q = r & 3;
        Wl[r][k] = W_hh[(size_t)(q * H_ + p * 4 + u) * H_ + k];
    }
    if (tid < 16) { int u = tid >> 2, q = tid & 3; bhh_l[tid] = b_hh[q * H_ + p * 4 + u]; }
    if (tid < 128) c_s[tid >> 2][tid & 3] = 0.f;
    __syncthreads();

    const int r = tid & 15;   // local gate-row
    const int b = tid >> 4;   // batch 0..31
    float* hb0 = hbuf;
    float* hb1 = hbuf + B_ * H_;

    for (int t = 0; t < S_; ++t) {
        const float* hcur = (t & 1) ? hb1 : hb0;
        float*       hnxt = (t & 1) ? hb0 : hb1;

        // ---- dot: pre_s[b][r] = Wl[r][:] . h[b][:] ----
        const float* hrow = hcur + b * H_;
        float acc = 0.f;
        #pragma unroll 8
        for (int k = 0; k < H_; k += 4) {
            float4 w  = *(const float4*)&Wl[r][k];
            float4 h4 = *(const float4*)&hrow[k];
            acc += w.x * h4.x + w.y * h4.y + w.z * h4.z + w.w * h4.w;
        }
        pre_s[b][r] = acc;
        __syncthreads();

        // ---- gate epilogue (128 threads: one per (b,u)) ----
        if (tid < 128) {
            int bb = tid >> 2, u = tid & 3;
            int j  = p * 4 + u;
            int xv = x[bb * S_ + t];
            const float* Tv = T + (size_t)xv * G4H;
            float pi = pre_s[bb][u * 4 + 0] + Tv[0 * H_ + j] + bhh_l[u * 4 + 0];
            float pf = pre_s[bb][u * 4 + 1] + Tv[1 * H_ + j] + bhh_l[u * 4 + 1];
            float pg = pre_s[bb][u * 4 + 2] + Tv[2 * H_ + j] + bhh_l[u * 4 + 2];
            float po = pre_s[bb][u * 4 + 3] + Tv[3 * H_ + j] + bhh_l[u * 4 + 3];
            float ig = 1.f / (1.f + expf(-pi));
            float fg = 1.f / (1.f + expf(-pf));
            float gg = tanhf(pg);
            float og = 1.f / (1.f + expf(-po));
            float c  = fg * c_s[bb][u] + ig * gg;
            float h  = og * tanhf(c);
            c_s[bb][u] = c;
            hnxt[bb * H_ + j] = h;
            h_all[(size_t)bb * (S_ * H_) + (size_t)t * H_ + j] = h;
        }

        // ---- device-scope grid barrier ----
        __threadfence();
        __syncthreads();
        if (tid == 0) {
            __hip_atomic_fetch_add(bar, 1, __ATOMIC_ACQ_REL, __HIP_MEMORY_SCOPE_AGENT);
            int tgt = 256 * (t + 1);
            while (__hip_atomic_load(bar, __ATOMIC_ACQUIRE, __HIP_MEMORY_SCOPE_AGENT) < tgt)
                __builtin_amdgcn_s_sleep(4);
        }
        __syncthreads();
        __threadfence();
    }
}

// ---------------- K3: expert GEMM  C[m][n] = A[m][:] . Bw[n][:] + be[n] ----------------
// A = h_all [32768 x 1024], Bw = We viewed [1280 x 1024] (n = e*128+v)
__global__ __launch_bounds__(256) void expert_gemm(
    const float* __restrict__ A, const float* __restrict__ Bw,
    const float* __restrict__ be, float* __restrict__ out)
{
    __shared__ float As[16][64];
    __shared__ float Bs[16][64];
    const int M = B_ * S_;                 // 32768
    int bm = blockIdx.x & 511;             // M/64
    int bn = blockIdx.x >> 9;              // 0..19
    int m0 = bm * 64, n0 = bn * 64;
    int tid = threadIdx.x;
    int tx = tid & 15, ty = tid >> 4;
    int arow = tid >> 2, ak = (tid & 3) * 4;

    float acc[4][4] = {};
    for (int k0 = 0; k0 < H_; k0 += 16) {
        float4 a4 = *(const float4*)&A[(size_t)(m0 + arow) * H_ + k0 + ak];
        float4 b4 = *(const float4*)&Bw[(size_t)(n0 + arow) * H_ + k0 + ak];
        As[ak + 0][arow] = a4.x; As[ak + 1][arow] = a4.y;
        As[ak + 2][arow] = a4.z; As[ak + 3][arow] = a4.w;
        Bs[ak + 0][arow] = b4.x; Bs[ak + 1][arow] = b4.y;
        Bs[ak + 2][arow] = b4.z; Bs[ak + 3][arow] = b4.w;
        __syncthreads();
        #pragma unroll
        for (int kk = 0; kk < 16; ++kk) {
            float4 av = *(const float4*)&As[kk][ty * 4];
            float4 bv = *(const float4*)&Bs[kk][tx * 4];
            float ar[4] = {av.x, av.y, av.z, av.w};
            float br[4] = {bv.x, bv.y, bv.z, bv.w};
            #pragma unroll
            for (int i = 0; i < 4; ++i)
                #pragma unroll
                for (int j = 0; j < 4; ++j) acc[i][j] += ar[i] * br[j];
        }
        __syncthreads();
    }

    int e  = n0 >> 7;
    int v0 = n0 & 127;
    #pragma unroll
    for (int i = 0; i < 4; ++i) {
        int m = m0 + ty * 4 + i;
        float4 o;
        o.x = acc[i][0] + be[n0 + tx * 4 + 0];
        o.y = acc[i][1] + be[n0 + tx * 4 + 1];
        o.z = acc[i][2] + be[n0 + tx * 4 + 2];
        o.w = acc[i][3] + be[n0 + tx * 4 + 3];
        *(float4*)(out + (size_t)e * ((size_t)M * V_) + (size_t)m * V_ + v0 + tx * 4) = o;
    }
}

// ---------------- K4: gating softmax ----------------
__global__ __launch_bounds__(256) void gating_kernel(
    const float* __restrict__ h_all, const float* __restrict__ Wg,
    const float* __restrict__ bg, float* __restrict__ gate_out)
{
    int b = blockIdx.x;
    int tid = threadIdx.x;
    __shared__ float red[NE_][256];
    const float* h = h_all + (size_t)b * (S_ * H_) + (size_t)(S_ - 1) * H_;
    float p[NE_];
    #pragma unroll
    for (int e = 0; e < NE_; ++e) p[e] = 0.f;
    for (int k = tid; k < H_; k += 256) {
        float hv = h[k];
        #pragma unroll
        for (int e = 0; e < NE_; ++e) p[e] += hv * Wg[e * H_ + k];
    }
    #pragma unroll
    for (int e = 0; e < NE_; ++e) red[e][tid] = p[e];
    __syncthreads();
    for (int s = 128; s > 0; s >>= 1) {
        if (tid < s) {
            #pragma unroll
            for (int e = 0; e < NE_; ++e) red[e][tid] += red[e][tid + s];
        }
        __syncthreads();
    }
    if (tid == 0) {
        float lg[NE_], mx = -1e30f;
        #pragma unroll
        for (int e = 0; e < NE_; ++e) { lg[e] = red[e][0] + bg[e]; mx = fmaxf(mx, lg[e]); }
        float s = 0.f;
        #pragma unroll
        for (int e = 0; e < NE_; ++e) { lg[e] = expf(lg[e] - mx); s += lg[e]; }
        #pragma unroll
        for (int e = 0; e < NE_; ++e) gate_out[b * NE_ + e] = lg[e] / s;
    }
}

// ---------------- K5: combine ----------------
__global__ __launch_bounds__(256) void combine_kernel(
    const float* __restrict__ exp_out, const float* __restrict__ gate,
    float* __restrict__ comb)
{
    int idx = blockIdx.x * 256 + threadIdx.x;  // < 4194304
    int b = idx >> 17;                         // / (S*V)
    float acc = 0.f;
    #pragma unroll
    for (int e = 0; e < NE_; ++e)
        acc += gate[b * NE_ + e] * exp_out[(size_t)e * (size_t)(B_ * S_ * V_) + idx];
    comb[idx] = acc;
}

extern "C" void kernel_launch(void* const* d_in, const int* in_sizes, int n_in,
                              void* d_out, int out_size, void* d_ws, size_t ws_size,
                              hipStream_t stream)
{
    const int*   x    = (const int*)  d_in[0];
    const float* emb  = (const float*)d_in[1];
    const float* W_ih = (const float*)d_in[2];
    const float* W_hh = (const float*)d_in[3];
    const float* b_ih = (const float*)d_in[4];
    const float* b_hh = (const float*)d_in[5];
    const float* We   = (const float*)d_in[6];
    const float* be   = (const float*)d_in[7];
    const float* Wg   = (const float*)d_in[8];
    const float* bg   = (const float*)d_in[9];

    float* out     = (float*)d_out;
    float* comb    = out;                               // [B,S,V]  4,194,304
    float* exp_out = out + 4194304;                     // [NE,B,S,V] 41,943,040
    float* gate    = out + 4194304 + 41943040;          // [B,NE] 320

    char*  ws    = (char*)d_ws;
    float* T     = (float*)ws;                          // 2 MB
    float* hbuf  = (float*)(ws + (2u << 20));           // 256 KB (double buffer h)
    int*   bar   = (int*)  (ws + (2u << 20) + (256u << 10));
    float* h_all = (float*)(ws + (4u << 20));           // 134 MB [B,S,H]

    // zero h double-buffer (h0 = 0) and barrier counter — required every replay
    hipMemsetAsync(ws + (2u << 20), 0, (256u << 10) + 256, stream);

    build_T      <<<2048, 256, 0, stream>>>(emb, W_ih, b_ih, T);
    lstm_scan    <<<256, 512, 0, stream>>>(x, T, W_hh, b_hh, hbuf, h_all, bar);
    expert_gemm  <<<512 * 20, 256, 0, stream>>>(h_all, We, be, exp_out);
    gating_kernel<<<B_, 256, 0, stream>>>(h_all, Wg, bg, gate);
    combine_kernel<<<4194304 / 256, 256, 0, stream>>>(exp_out, gate, comb);
}

// Round 2
// 75016.718 us; speedup vs baseline: 1.3911x; 1.3911x over previous
//
#include <hip/hip_runtime.h>
#include <math.h>

#define V_  128
#define E_  512
#define H_  1024
#define NE_ 10
#define B_  32
#define S_  1024
#define G4H (4*H_)   // 4096

// ---------------- K1: T[v][g] = sum_e emb[v][e]*W_ih[g][e] + b_ih[g] ----------------
__global__ __launch_bounds__(256) void build_T(
    const float* __restrict__ emb, const float* __restrict__ W_ih,
    const float* __restrict__ b_ih, float* __restrict__ T)
{
    int idx = blockIdx.x * 256 + threadIdx.x;    // over 4096*128
    int g = idx >> 7, v = idx & 127;
    const float* er = emb + v * E_;
    const float* wr = W_ih + (size_t)g * E_;
    float acc = b_ih[g];
    #pragma unroll 4
    for (int e = 0; e < E_; ++e) acc += er[e] * wr[e];
    T[v * G4H + g] = acc;
}

// ---------------- K2: persistent LSTM scan ----------------
// 256 blocks (one per CU), block p owns hidden units j = 4p..4p+3.
// W_hh rows for those units (16 rows x 1024) live in LDS for the whole scan.
// Grid sync: distributed flag barrier — block p release-stores step count into
// flags[p*16] (own cacheline); first wave of every block polls all 256 flags.
__global__ __launch_bounds__(512) void lstm_scan(
    const int* __restrict__ x, const float* __restrict__ T,
    const float* __restrict__ W_hh, const float* __restrict__ b_hh,
    float* __restrict__ hbuf, float* __restrict__ h_all, int* __restrict__ flags)
{
    const int p   = blockIdx.x;      // 0..255
    const int tid = threadIdx.x;     // 0..511

    // local row r = u*4+q  (unit u in 0..3, gate q: 0=i,1=f,2=g,3=o), pad rows by 4 floats
    __shared__ float Wl[16][1028];
    __shared__ float pre_s[32][16];
    __shared__ float c_s[32][4];
    __shared__ float bhh_l[16];

    for (int idx = tid; idx < 16 * 1024; idx += 512) {
        int r = idx >> 10, k = idx & 1023;
        int u = r >> 2, q = r & 3;
        Wl[r][k] = W_hh[(size_t)(q * H_ + p * 4 + u) * H_ + k];
    }
    if (tid < 16) { int u = tid >> 2, q = tid & 3; bhh_l[tid] = b_hh[q * H_ + p * 4 + u]; }
    if (tid < 128) c_s[tid >> 2][tid & 3] = 0.f;
    __syncthreads();

    const int r = tid & 15;   // local gate-row
    const int b = tid >> 4;   // batch 0..31
    float* hb0 = hbuf;
    float* hb1 = hbuf + B_ * H_;

    for (int t = 0; t < S_; ++t) {
        const float* hcur = (t & 1) ? hb1 : hb0;
        float*       hnxt = (t & 1) ? hb0 : hb1;

        // ---- dot: pre_s[b][r] = Wl[r][:] . h[b][:] ----
        const float* hrow = hcur + b * H_;
        float acc = 0.f;
        #pragma unroll 8
        for (int k = 0; k < H_; k += 4) {
            float4 w  = *(const float4*)&Wl[r][k];
            float4 h4 = *(const float4*)&hrow[k];
            acc += w.x * h4.x + w.y * h4.y + w.z * h4.z + w.w * h4.w;
        }
        pre_s[b][r] = acc;
        __syncthreads();

        // ---- gate epilogue (128 threads: one per (b,u)) ----
        if (tid < 128) {
            int bb = tid >> 2, u = tid & 3;
            int j  = p * 4 + u;
            int xv = x[bb * S_ + t];
            const float* Tv = T + (size_t)xv * G4H;
            float pi = pre_s[bb][u * 4 + 0] + Tv[0 * H_ + j] + bhh_l[u * 4 + 0];
            float pf = pre_s[bb][u * 4 + 1] + Tv[1 * H_ + j] + bhh_l[u * 4 + 1];
            float pg = pre_s[bb][u * 4 + 2] + Tv[2 * H_ + j] + bhh_l[u * 4 + 2];
            float po = pre_s[bb][u * 4 + 3] + Tv[3 * H_ + j] + bhh_l[u * 4 + 3];
            float ig = 1.f / (1.f + expf(-pi));
            float fg = 1.f / (1.f + expf(-pf));
            float gg = tanhf(pg);
            float og = 1.f / (1.f + expf(-po));
            float c  = fg * c_s[bb][u] + ig * gg;
            float h  = og * tanhf(c);
            c_s[bb][u] = c;
            hnxt[bb * H_ + j] = h;
            h_all[(size_t)bb * (S_ * H_) + (size_t)t * H_ + j] = h;
        }

        if (t == S_ - 1) break;   // nothing reads h after the last step

        // ---- distributed-flag grid barrier ----
        __threadfence();          // make this block's h stores device-visible
        __syncthreads();
        if (tid < 64) {
            if (tid == 0)
                __hip_atomic_store(&flags[p * 16], t + 1,
                                   __ATOMIC_RELEASE, __HIP_MEMORY_SCOPE_AGENT);
            const int i0 = tid * 4;            // this lane watches blocks i0..i0+3
            for (;;) {
                int m0 = __hip_atomic_load(&flags[(i0 + 0) * 16], __ATOMIC_ACQUIRE, __HIP_MEMORY_SCOPE_AGENT);
                int m1 = __hip_atomic_load(&flags[(i0 + 1) * 16], __ATOMIC_ACQUIRE, __HIP_MEMORY_SCOPE_AGENT);
                int m2 = __hip_atomic_load(&flags[(i0 + 2) * 16], __ATOMIC_ACQUIRE, __HIP_MEMORY_SCOPE_AGENT);
                int m3 = __hip_atomic_load(&flags[(i0 + 3) * 16], __ATOMIC_ACQUIRE, __HIP_MEMORY_SCOPE_AGENT);
                int mn = min(min(m0, m1), min(m2, m3));
                if (__all(mn >= t + 1)) break;
                __builtin_amdgcn_s_sleep(2);
            }
        }
        __syncthreads();
    }
}

// ---------------- K3: expert GEMM  C[m][n] = A[m][:] . Bw[n][:] + be[n] ----------------
// A = h_all [32768 x 1024], Bw = We viewed [1280 x 1024] (n = e*128+v)
__global__ __launch_bounds__(256) void expert_gemm(
    const float* __restrict__ A, const float* __restrict__ Bw,
    const float* __restrict__ be, float* __restrict__ out)
{
    __shared__ float As[16][64];
    __shared__ float Bs[16][64];
    const int M = B_ * S_;                 // 32768
    int bm = blockIdx.x & 511;             // M/64
    int bn = blockIdx.x >> 9;              // 0..19
    int m0 = bm * 64, n0 = bn * 64;
    int tid = threadIdx.x;
    int tx = tid & 15, ty = tid >> 4;
    int arow = tid >> 2, ak = (tid & 3) * 4;

    float acc[4][4] = {};
    for (int k0 = 0; k0 < H_; k0 += 16) {
        float4 a4 = *(const float4*)&A[(size_t)(m0 + arow) * H_ + k0 + ak];
        float4 b4 = *(const float4*)&Bw[(size_t)(n0 + arow) * H_ + k0 + ak];
        As[ak + 0][arow] = a4.x; As[ak + 1][arow] = a4.y;
        As[ak + 2][arow] = a4.z; As[ak + 3][arow] = a4.w;
        Bs[ak + 0][arow] = b4.x; Bs[ak + 1][arow] = b4.y;
        Bs[ak + 2][arow] = b4.z; Bs[ak + 3][arow] = b4.w;
        __syncthreads();
        #pragma unroll
        for (int kk = 0; kk < 16; ++kk) {
            float4 av = *(const float4*)&As[kk][ty * 4];
            float4 bv = *(const float4*)&Bs[kk][tx * 4];
            float ar[4] = {av.x, av.y, av.z, av.w};
            float br[4] = {bv.x, bv.y, bv.z, bv.w};
            #pragma unroll
            for (int i = 0; i < 4; ++i)
                #pragma unroll
                for (int j = 0; j < 4; ++j) acc[i][j] += ar[i] * br[j];
        }
        __syncthreads();
    }

    int e  = n0 >> 7;
    int v0 = n0 & 127;
    #pragma unroll
    for (int i = 0; i < 4; ++i) {
        int m = m0 + ty * 4 + i;
        float4 o;
        o.x = acc[i][0] + be[n0 + tx * 4 + 0];
        o.y = acc[i][1] + be[n0 + tx * 4 + 1];
        o.z = acc[i][2] + be[n0 + tx * 4 + 2];
        o.w = acc[i][3] + be[n0 + tx * 4 + 3];
        *(float4*)(out + (size_t)e * ((size_t)M * V_) + (size_t)m * V_ + v0 + tx * 4) = o;
    }
}

// ---------------- K4: gating softmax ----------------
__global__ __launch_bounds__(256) void gating_kernel(
    const float* __restrict__ h_all, const float* __restrict__ Wg,
    const float* __restrict__ bg, float* __restrict__ gate_out)
{
    int b = blockIdx.x;
    int tid = threadIdx.x;
    __shared__ float red[NE_][256];
    const float* h = h_all + (size_t)b * (S_ * H_) + (size_t)(S_ - 1) * H_;
    float p[NE_];
    #pragma unroll
    for (int e = 0; e < NE_; ++e) p[e] = 0.f;
    for (int k = tid; k < H_; k += 256) {
        float hv = h[k];
        #pragma unroll
        for (int e = 0; e < NE_; ++e) p[e] += hv * Wg[e * H_ + k];
    }
    #pragma unroll
    for (int e = 0; e < NE_; ++e) red[e][tid] = p[e];
    __syncthreads();
    for (int s = 128; s > 0; s >>= 1) {
        if (tid < s) {
            #pragma unroll
            for (int e = 0; e < NE_; ++e) red[e][tid] += red[e][tid + s];
        }
        __syncthreads();
    }
    if (tid == 0) {
        float lg[NE_], mx = -1e30f;
        #pragma unroll
        for (int e = 0; e < NE_; ++e) { lg[e] = red[e][0] + bg[e]; mx = fmaxf(mx, lg[e]); }
        float s = 0.f;
        #pragma unroll
        for (int e = 0; e < NE_; ++e) { lg[e] = expf(lg[e] - mx); s += lg[e]; }
        #pragma unroll
        for (int e = 0; e < NE_; ++e) gate_out[b * NE_ + e] = lg[e] / s;
    }
}

// ---------------- K5: combine ----------------
__global__ __launch_bounds__(256) void combine_kernel(
    const float* __restrict__ exp_out, const float* __restrict__ gate,
    float* __restrict__ comb)
{
    int idx = blockIdx.x * 256 + threadIdx.x;  // < 4194304
    int b = idx >> 17;                         // / (S*V)
    float acc = 0.f;
    #pragma unroll
    for (int e = 0; e < NE_; ++e)
        acc += gate[b * NE_ + e] * exp_out[(size_t)e * (size_t)(B_ * S_ * V_) + idx];
    comb[idx] = acc;
}

extern "C" void kernel_launch(void* const* d_in, const int* in_sizes, int n_in,
                              void* d_out, int out_size, void* d_ws, size_t ws_size,
                              hipStream_t stream)
{
    const int*   x    = (const int*)  d_in[0];
    const float* emb  = (const float*)d_in[1];
    const float* W_ih = (const float*)d_in[2];
    const float* W_hh = (const float*)d_in[3];
    const float* b_ih = (const float*)d_in[4];
    const float* b_hh = (const float*)d_in[5];
    const float* We   = (const float*)d_in[6];
    const float* be   = (const float*)d_in[7];
    const float* Wg   = (const float*)d_in[8];
    const float* bg   = (const float*)d_in[9];

    float* out     = (float*)d_out;
    float* comb    = out;                               // [B,S,V]  4,194,304
    float* exp_out = out + 4194304;                     // [NE,B,S,V] 41,943,040
    float* gate    = out + 4194304 + 41943040;          // [B,NE] 320

    char*  ws    = (char*)d_ws;
    float* T     = (float*)ws;                          // 2 MB
    float* hbuf  = (float*)(ws + (2u << 20));           // 256 KB (double buffer h)
    int*   flags = (int*)  (ws + (2u << 20) + (256u << 10));  // 256 x 64B slots = 16 KB
    float* h_all = (float*)(ws + (4u << 20));           // 134 MB [B,S,H]

    // zero h double-buffer (h0 = 0) and barrier flags — required every replay
    hipMemsetAsync(ws + (2u << 20), 0, (256u << 10) + (16u << 10), stream);

    build_T      <<<2048, 256, 0, stream>>>(emb, W_ih, b_ih, T);
    lstm_scan    <<<256, 512, 0, stream>>>(x, T, W_hh, b_hh, hbuf, h_all, flags);
    expert_gemm  <<<512 * 20, 256, 0, stream>>>(h_all, We, be, exp_out);
    gating_kernel<<<B_, 256, 0, stream>>>(h_all, Wg, bg, gate);
    combine_kernel<<<4194304 / 256, 256, 0, stream>>>(exp_out, gate, comb);
}

// Round 3
// 6784.738 us; speedup vs baseline: 15.3815x; 11.0567x over previous
//
#include <hip/hip_runtime.h>
#include <hip/hip_bf16.h>
#include <math.h>

#define V_  128
#define E_  512
#define H_  1024
#define NE_ 10
#define B_  32
#define S_  1024
#define G4H (4*H_)   // 4096

typedef short bf16x8 __attribute__((ext_vector_type(8)));
typedef float f32x4  __attribute__((ext_vector_type(4)));

__device__ __forceinline__ short f2bf(float f) {
    __hip_bfloat16 h = __float2bfloat16(f);
    short s; __builtin_memcpy(&s, &h, 2); return s;
}

// ---- device-coherent (L1/L2-bypass) memory ops: no fences needed ----
__device__ __forceinline__ int4 gload4_sc(const void* p) {
    int4 r;
    asm volatile("global_load_dwordx4 %0, %1, off sc0 sc1" : "=&v"(r) : "v"(p));
    return r;
}
__device__ __forceinline__ int gload1_sc(const void* p) {
    int r;
    asm volatile("global_load_dword %0, %1, off sc0 sc1" : "=&v"(r) : "v"(p));
    return r;
}
__device__ __forceinline__ void gstore2_sc(void* p, int2 v) {
    asm volatile("global_store_dwordx2 %0, %1, off sc0 sc1" :: "v"(p), "v"(v) : "memory");
}
__device__ __forceinline__ void gstore1_sc(void* p, int v) {
    asm volatile("global_store_dword %0, %1, off sc0 sc1" :: "v"(p), "v"(v) : "memory");
}
// wait for loads AND pin the compiler: reg-only MFMA must not hoist past this (rule #18)
#define WAITCNT0() do { asm volatile("s_waitcnt vmcnt(0)" ::: "memory"); \
                        __builtin_amdgcn_sched_barrier(0); } while (0)

// ---------------- K1: T[v][g] = sum_e emb[v][e]*W_ih[g][e] + b_ih[g] ----------------
__global__ __launch_bounds__(256) void build_T(
    const float* __restrict__ emb, const float* __restrict__ W_ih,
    const float* __restrict__ b_ih, float* __restrict__ T)
{
    int idx = blockIdx.x * 256 + threadIdx.x;    // over 4096*128
    int g = idx >> 7, v = idx & 127;
    const float* er = emb + v * E_;
    const float* wr = W_ih + (size_t)g * E_;
    float acc = b_ih[g];
    #pragma unroll 4
    for (int e = 0; e < E_; ++e) acc += er[e] * wr[e];
    T[v * G4H + g] = acc;
}

// ---------------- K2: persistent LSTM scan, MFMA + fence-free L3 exchange ----------------
// 256 blocks x 512 thr. Block p owns hidden units 4p..4p+3 (16 gate rows).
// W_hh fragments live in VGPRs for the whole scan. h exchanged as bf16 via sc0/sc1
// (coherent-point) loads/stores; flag barrier with NO fences.
__global__ __launch_bounds__(512) void lstm_scan(
    const int* __restrict__ x, const float* __restrict__ T,
    const float* __restrict__ W_hh, const float* __restrict__ b_hh,
    ushort* __restrict__ hbuf, float* __restrict__ h_all, int* __restrict__ flags)
{
    const int p = blockIdx.x, tid = threadIdx.x;
    const int lane = tid & 63, wave = tid >> 6;     // 8 waves
    const int m = lane & 15, kg = lane >> 4;        // MFMA row / k-group

    __shared__ float  part_lds[8 * 512];   // per-wave partial D tiles (16 KB)
    __shared__ float  pre_s[32][17];
    __shared__ float  c_s[32][4];
    __shared__ float  bhh_l[16];
    __shared__ ushort hout[32][4];
    __shared__ float  lds_pad[16384];      // 64 KB: force 1 block/CU (barrier tail latency)
    if ((((size_t)x) & 4095) == 1) lds_pad[tid] = 0.f;   // never true at runtime

    // ---- persistent A-fragments: lane m holds W row grow=(m&3)*H + 4p + (m>>2) ----
    // A[m][k], k = wave*128 + kk*32 + kg*8 + j  (j=0..7)
    bf16x8 afrag[4];
    {
        const float* wbase = W_hh + (size_t)((m & 3) * H_ + p * 4 + (m >> 2)) * H_;
        #pragma unroll
        for (int kk = 0; kk < 4; ++kk) {
            int kbase = wave * 128 + kk * 32 + kg * 8;
            float4 w0 = *(const float4*)(wbase + kbase);
            float4 w1 = *(const float4*)(wbase + kbase + 4);
            bf16x8 a;
            a[0]=f2bf(w0.x); a[1]=f2bf(w0.y); a[2]=f2bf(w0.z); a[3]=f2bf(w0.w);
            a[4]=f2bf(w1.x); a[5]=f2bf(w1.y); a[6]=f2bf(w1.z); a[7]=f2bf(w1.w);
            afrag[kk] = a;
        }
    }
    if (tid < 16)  bhh_l[tid] = b_hh[(tid & 3) * H_ + p * 4 + (tid >> 2)];
    if (tid < 128) c_s[tid >> 2][tid & 3] = 0.f;

    // B-frag offsets (ushort units): batch n = c*16+m, k as above
    int boff[8];
    #pragma unroll
    for (int c = 0; c < 2; ++c)
        #pragma unroll
        for (int kk = 0; kk < 4; ++kk)
            boff[c * 4 + kk] = (c * 16 + m) * H_ + wave * 128 + kk * 32 + kg * 8;

    ushort* hb0 = hbuf;
    ushort* hb1 = hbuf + B_ * H_;
    __syncthreads();

    for (int t = 0; t < S_; ++t) {
        const ushort* hrd = (t & 1) ? hb0 : hb1;   // h_{t-1}; t=0 -> hb1 (zeroed)
        ushort*       hwr = (t & 1) ? hb1 : hb0;   // h_t

        // ---- load h_{t-1} B-fragments from coherence point ----
        int4 braw[8];
        #pragma unroll
        for (int i = 0; i < 8; ++i) braw[i] = gload4_sc(hrd + boff[i]);
        WAITCNT0();

        // ---- MFMA: pre[16 rows][32 batch], K split over waves ----
        f32x4 acc0 = {0.f,0.f,0.f,0.f}, acc1 = {0.f,0.f,0.f,0.f};
        #pragma unroll
        for (int kk = 0; kk < 4; ++kk) {
            bf16x8 b0, b1;
            __builtin_memcpy(&b0, &braw[kk],     16);
            __builtin_memcpy(&b1, &braw[4 + kk], 16);
            acc0 = __builtin_amdgcn_mfma_f32_16x16x32_bf16(afrag[kk], b0, acc0, 0, 0, 0);
            acc1 = __builtin_amdgcn_mfma_f32_16x16x32_bf16(afrag[kk], b1, acc1, 0, 0, 0);
        }
        // D layout: row=(kg*4+d), col=m
        #pragma unroll
        for (int d = 0; d < 4; ++d) {
            part_lds[wave * 512 +       (kg * 4 + d) * 16 + m] = acc0[d];
            part_lds[wave * 512 + 256 + (kg * 4 + d) * 16 + m] = acc1[d];
        }
        __syncthreads();

        // ---- cross-wave K reduction ----
        {
            float s = 0.f;
            #pragma unroll
            for (int w = 0; w < 8; ++w) s += part_lds[w * 512 + tid];
            int b  = ((tid >> 8) << 4) | (tid & 15);
            int mm = (tid >> 4) & 15;
            pre_s[b][mm] = s;
        }
        __syncthreads();

        // ---- gate epilogue: one thread per (batch, unit) ----
        if (tid < 128) {
            int bb = tid >> 2, u = tid & 3;
            int j  = p * 4 + u;
            int xv = x[bb * S_ + t];
            const float* Tv = T + (size_t)xv * G4H;
            float pi = pre_s[bb][u*4+0] + Tv[0*H_ + j] + bhh_l[u*4+0];
            float pf = pre_s[bb][u*4+1] + Tv[1*H_ + j] + bhh_l[u*4+1];
            float pg = pre_s[bb][u*4+2] + Tv[2*H_ + j] + bhh_l[u*4+2];
            float po = pre_s[bb][u*4+3] + Tv[3*H_ + j] + bhh_l[u*4+3];
            float ig = 1.f/(1.f+expf(-pi));
            float fg = 1.f/(1.f+expf(-pf));
            float gg = tanhf(pg);
            float og = 1.f/(1.f+expf(-po));
            float c  = fg * c_s[bb][u] + ig * gg;
            float h  = og * tanhf(c);
            c_s[bb][u] = c;
            h_all[(size_t)bb * (S_*H_) + (size_t)t * H_ + j] = h;
            hout[bb][u] = (ushort)f2bf(h);
        }
        if (t == S_ - 1) break;
        __syncthreads();

        // ---- publish h_t (bf16, 8B per batch) to coherence point ----
        if (tid < 32) {
            int2 hv = *(const int2*)&hout[tid][0];
            gstore2_sc(hwr + tid * H_ + p * 4, hv);
        }
        // ---- fence-free flag barrier (wave 0) ----
        if (wave == 0) {
            asm volatile("s_waitcnt vmcnt(0)" ::: "memory");   // h_t is at L3
            if (tid == 0) gstore1_sc(flags + p * 16, t + 1);
            const int i0 = lane * 4;
            for (;;) {
                int f0 = gload1_sc(flags + (i0+0) * 16);
                int f1 = gload1_sc(flags + (i0+1) * 16);
                int f2 = gload1_sc(flags + (i0+2) * 16);
                int f3 = gload1_sc(flags + (i0+3) * 16);
                WAITCNT0();
                int mn = min(min(f0, f1), min(f2, f3));
                if (__all(mn >= t + 1)) break;
                __builtin_amdgcn_s_sleep(1);
            }
        }
        __syncthreads();
    }
}

// ---------------- K3: expert GEMM  C[m][n] = A[m][:] . Bw[n][:] + be[n] ----------------
__global__ __launch_bounds__(256) void expert_gemm(
    const float* __restrict__ A, const float* __restrict__ Bw,
    const float* __restrict__ be, float* __restrict__ out)
{
    __shared__ float As[16][64];
    __shared__ float Bs[16][64];
    const int M = B_ * S_;                 // 32768
    int bm = blockIdx.x & 511;
    int bn = blockIdx.x >> 9;              // 0..19
    int m0 = bm * 64, n0 = bn * 64;
    int tid = threadIdx.x;
    int tx = tid & 15, ty = tid >> 4;
    int arow = tid >> 2, ak = (tid & 3) * 4;

    float acc[4][4] = {};
    for (int k0 = 0; k0 < H_; k0 += 16) {
        float4 a4 = *(const float4*)&A[(size_t)(m0 + arow) * H_ + k0 + ak];
        float4 b4 = *(const float4*)&Bw[(size_t)(n0 + arow) * H_ + k0 + ak];
        As[ak + 0][arow] = a4.x; As[ak + 1][arow] = a4.y;
        As[ak + 2][arow] = a4.z; As[ak + 3][arow] = a4.w;
        Bs[ak + 0][arow] = b4.x; Bs[ak + 1][arow] = b4.y;
        Bs[ak + 2][arow] = b4.z; Bs[ak + 3][arow] = b4.w;
        __syncthreads();
        #pragma unroll
        for (int kk = 0; kk < 16; ++kk) {
            float4 av = *(const float4*)&As[kk][ty * 4];
            float4 bv = *(const float4*)&Bs[kk][tx * 4];
            float ar[4] = {av.x, av.y, av.z, av.w};
            float br[4] = {bv.x, bv.y, bv.z, bv.w};
            #pragma unroll
            for (int i = 0; i < 4; ++i)
                #pragma unroll
                for (int j = 0; j < 4; ++j) acc[i][j] += ar[i] * br[j];
        }
        __syncthreads();
    }

    int e  = n0 >> 7;
    int v0 = n0 & 127;
    #pragma unroll
    for (int i = 0; i < 4; ++i) {
        int mr = m0 + ty * 4 + i;
        float4 o;
        o.x = acc[i][0] + be[n0 + tx * 4 + 0];
        o.y = acc[i][1] + be[n0 + tx * 4 + 1];
        o.z = acc[i][2] + be[n0 + tx * 4 + 2];
        o.w = acc[i][3] + be[n0 + tx * 4 + 3];
        *(float4*)(out + (size_t)e * ((size_t)M * V_) + (size_t)mr * V_ + v0 + tx * 4) = o;
    }
}

// ---------------- K4: gating softmax ----------------
__global__ __launch_bounds__(256) void gating_kernel(
    const float* __restrict__ h_all, const float* __restrict__ Wg,
    const float* __restrict__ bg, float* __restrict__ gate_out)
{
    int b = blockIdx.x;
    int tid = threadIdx.x;
    __shared__ float red[NE_][256];
    const float* h = h_all + (size_t)b * (S_ * H_) + (size_t)(S_ - 1) * H_;
    float pa[NE_];
    #pragma unroll
    for (int e = 0; e < NE_; ++e) pa[e] = 0.f;
    for (int k = tid; k < H_; k += 256) {
        float hv = h[k];
        #pragma unroll
        for (int e = 0; e < NE_; ++e) pa[e] += hv * Wg[e * H_ + k];
    }
    #pragma unroll
    for (int e = 0; e < NE_; ++e) red[e][tid] = pa[e];
    __syncthreads();
    for (int s = 128; s > 0; s >>= 1) {
        if (tid < s) {
            #pragma unroll
            for (int e = 0; e < NE_; ++e) red[e][tid] += red[e][tid + s];
        }
        __syncthreads();
    }
    if (tid == 0) {
        float lg[NE_], mx = -1e30f;
        #pragma unroll
        for (int e = 0; e < NE_; ++e) { lg[e] = red[e][0] + bg[e]; mx = fmaxf(mx, lg[e]); }
        float s = 0.f;
        #pragma unroll
        for (int e = 0; e < NE_; ++e) { lg[e] = expf(lg[e] - mx); s += lg[e]; }
        #pragma unroll
        for (int e = 0; e < NE_; ++e) gate_out[b * NE_ + e] = lg[e] / s;
    }
}

// ---------------- K5: combine ----------------
__global__ __launch_bounds__(256) void combine_kernel(
    const float* __restrict__ exp_out, const float* __restrict__ gate,
    float* __restrict__ comb)
{
    int idx = blockIdx.x * 256 + threadIdx.x;  // < 4194304
    int b = idx >> 17;
    float acc = 0.f;
    #pragma unroll
    for (int e = 0; e < NE_; ++e)
        acc += gate[b * NE_ + e] * exp_out[(size_t)e * (size_t)(B_ * S_ * V_) + idx];
    comb[idx] = acc;
}

extern "C" void kernel_launch(void* const* d_in, const int* in_sizes, int n_in,
                              void* d_out, int out_size, void* d_ws, size_t ws_size,
                              hipStream_t stream)
{
    const int*   x    = (const int*)  d_in[0];
    const float* emb  = (const float*)d_in[1];
    const float* W_ih = (const float*)d_in[2];
    const float* W_hh = (const float*)d_in[3];
    const float* b_ih = (const float*)d_in[4];
    const float* b_hh = (const float*)d_in[5];
    const float* We   = (const float*)d_in[6];
    const float* be   = (const float*)d_in[7];
    const float* Wg   = (const float*)d_in[8];
    const float* bg   = (const float*)d_in[9];

    float* out     = (float*)d_out;
    float* comb    = out;                               // [B,S,V]
    float* exp_out = out + 4194304;                     // [NE,B,S,V]
    float* gate    = out + 4194304 + 41943040;          // [B,NE]

    char*   ws    = (char*)d_ws;
    float*  T     = (float*)ws;                               // 2 MB
    ushort* hbuf  = (ushort*)(ws + (2u << 20));               // 2 x 64 KB bf16
    int*    flags = (int*)   (ws + (2u << 20) + (128u << 10));// 256 x 64 B
    float*  h_all = (float*) (ws + (4u << 20));               // 134 MB [B,S,H]

    // zero h double-buffer (h0 = 0) and barrier flags — required every replay
    hipMemsetAsync(ws + (2u << 20), 0, (144u << 10), stream);

    build_T      <<<2048, 256, 0, stream>>>(emb, W_ih, b_ih, T);
    lstm_scan    <<<256, 512, 0, stream>>>(x, T, W_hh, b_hh, hbuf, h_all, flags);
    expert_gemm  <<<512 * 20, 256, 0, stream>>>(h_all, We, be, exp_out);
    gating_kernel<<<B_, 256, 0, stream>>>(h_all, Wg, bg, gate);
    combine_kernel<<<4194304 / 256, 256, 0, stream>>>(exp_out, gate, comb);
}

// Round 4
// 5482.886 us; speedup vs baseline: 19.0336x; 1.2374x over previous
//
#include <hip/hip_runtime.h>
#include <hip/hip_bf16.h>
#include <math.h>

#define V_  128
#define E_  512
#define H_  1024
#define NE_ 10
#define B_  32
#define S_  1024
#define G4H (4*H_)   // 4096

typedef short bf16x8 __attribute__((ext_vector_type(8)));
typedef float f32x4  __attribute__((ext_vector_type(4)));

__device__ __forceinline__ short f2bf(float f) {
    __hip_bfloat16 h = __float2bfloat16(f);
    short s; __builtin_memcpy(&s, &h, 2); return s;
}
__device__ __forceinline__ float bf2f(ushort u) {
    unsigned int x = ((unsigned int)u) << 16;
    float f; __builtin_memcpy(&f, &x, 4); return f;
}
__device__ __forceinline__ float sigf(float x) { return 1.f / (1.f + __expf(-x)); }
__device__ __forceinline__ float tanhfast(float x) { return 1.f - 2.f / (__expf(2.f * x) + 1.f); }

// ---- device-coherent (L1/L2-bypass) memory ops ----
__device__ __forceinline__ int4 gload4_sc(const void* p) {
    int4 r;
    asm volatile("global_load_dwordx4 %0, %1, off sc0 sc1" : "=&v"(r) : "v"(p));
    return r;
}
__device__ __forceinline__ int gload1_sc(const void* p) {
    int r;
    asm volatile("global_load_dword %0, %1, off sc0 sc1" : "=&v"(r) : "v"(p));
    return r;
}
__device__ __forceinline__ void gstore2_sc(void* p, int2 v) {
    asm volatile("global_store_dwordx2 %0, %1, off sc0 sc1" :: "v"(p), "v"(v) : "memory");
}
__device__ __forceinline__ void gstore1_sc(void* p, int v) {
    asm volatile("global_store_dword %0, %1, off sc0 sc1" :: "v"(p), "v"(v) : "memory");
}
// wait for loads AND pin the compiler: reg-only MFMA must not hoist past this (rule #18)
#define WAITCNT0() do { asm volatile("s_waitcnt vmcnt(0)" ::: "memory"); \
                        __builtin_amdgcn_sched_barrier(0); } while (0)

// ---------------- K1: T2[v][j*4+q] = emb[v] . W_ih[q*H+j] + b_ih[q*H+j] ----------------
__global__ __launch_bounds__(256) void build_T(
    const float* __restrict__ emb, const float* __restrict__ W_ih,
    const float* __restrict__ b_ih, float* __restrict__ T2)
{
    int idx = blockIdx.x * 256 + threadIdx.x;    // over 4096*128
    int g = idx >> 7, v = idx & 127;
    const float* er = emb + v * E_;
    const float* wr = W_ih + (size_t)g * E_;
    float acc = b_ih[g];
    #pragma unroll 4
    for (int e = 0; e < E_; ++e) acc += er[e] * wr[e];
    T2[v * G4H + (g & 1023) * 4 + (g >> 10)] = acc;   // [v][j][q] layout
}

// ---------------- K1b: We -> bf16 ----------------
__global__ __launch_bounds__(256) void conv_bf16(
    const float* __restrict__ src, ushort* __restrict__ dst, int n)
{
    int i = blockIdx.x * 256 + threadIdx.x;
    if (i < n) dst[i] = (ushort)f2bf(src[i]);
}

// ---------------- K2: persistent LSTM scan, per-wave producer-consumer flags ----------------
// 256 blocks x 512 thr (8 waves). Block p owns units 4p..4p+3 (16 gate rows).
// Wave w: k-slice (w&3)*256, batch-half w>>2. Each wave polls ONLY its 64 source
// blocks' flags, then loads + MFMAs. No full-grid barrier at all.
__global__ __launch_bounds__(512) void lstm_scan(
    const int* __restrict__ x, const float* __restrict__ T2,
    const float* __restrict__ W_hh, const float* __restrict__ b_hh,
    ushort* __restrict__ hbuf, ushort* __restrict__ h_all, int* __restrict__ flags)
{
    const int p = blockIdx.x, tid = threadIdx.x;
    const int lane = tid & 63, wave = tid >> 6;
    const int m = lane & 15, kg = lane >> 4;     // MFMA row / k-group
    const int kslice = wave & 3, chalf = wave >> 2;
    const int k0 = kslice * 256;

    __shared__ float part_lds[8 * 256];   // 8KB partials
    __shared__ float pre_s[32][17];
    __shared__ float bhh_l[16];

    // persistent A-fragments: lane m = gate row r; W row = (r&3)*H + 4p + (r>>2)
    bf16x8 afrag[8];
    {
        const float* wbase = W_hh + (size_t)((m & 3) * H_ + p * 4 + (m >> 2)) * H_;
        #pragma unroll
        for (int kk = 0; kk < 8; ++kk) {
            int kb = k0 + kk * 32 + kg * 8;
            float4 w0 = *(const float4*)(wbase + kb);
            float4 w1 = *(const float4*)(wbase + kb + 4);
            bf16x8 a;
            a[0]=f2bf(w0.x); a[1]=f2bf(w0.y); a[2]=f2bf(w0.z); a[3]=f2bf(w0.w);
            a[4]=f2bf(w1.x); a[5]=f2bf(w1.y); a[6]=f2bf(w1.z); a[7]=f2bf(w1.w);
            afrag[kk] = a;
        }
    }
    if (tid < 16) bhh_l[tid] = b_hh[(tid & 3) * H_ + p * 4 + (tid >> 2)];

    int boff[8];
    #pragma unroll
    for (int kk = 0; kk < 8; ++kk)
        boff[kk] = (chalf * 16 + m) * H_ + k0 + kk * 32 + kg * 8;

    // epilogue lane constants (wave 0): lane -> (batch bb, units u0,u0+1)
    const int bb = lane >> 1, u0 = (lane & 1) * 2;
    float c0 = 0.f, c1 = 0.f;

    ushort* hb0 = hbuf;
    ushort* hb1 = hbuf + B_ * H_;
    __syncthreads();

    for (int t = 0; t < S_; ++t) {
        const ushort* hrd = (t & 1) ? hb0 : hb1;   // h_{t-1}; t=0 -> zeroed hb1
        ushort*       hwr = (t & 1) ? hb1 : hb0;

        // ---- per-wave poll: my 64 source blocks must have published step t-1 ----
        {
            const int src = kslice * 64 + lane;
            for (;;) {
                int f = gload1_sc(flags + src * 16);
                WAITCNT0();
                if (__all(f >= t)) break;
                __builtin_amdgcn_s_sleep(1);
            }
        }

        // ---- load my B-fragments, MFMA (two independent chains) ----
        int4 braw[8];
        #pragma unroll
        for (int i = 0; i < 8; ++i) braw[i] = gload4_sc(hrd + boff[i]);
        WAITCNT0();
        f32x4 accA = {0.f,0.f,0.f,0.f}, accB = {0.f,0.f,0.f,0.f};
        #pragma unroll
        for (int kk = 0; kk < 4; ++kk) {
            bf16x8 b0, b1;
            __builtin_memcpy(&b0, &braw[kk * 2],     16);
            __builtin_memcpy(&b1, &braw[kk * 2 + 1], 16);
            accA = __builtin_amdgcn_mfma_f32_16x16x32_bf16(afrag[kk * 2],     b0, accA, 0, 0, 0);
            accB = __builtin_amdgcn_mfma_f32_16x16x32_bf16(afrag[kk * 2 + 1], b1, accB, 0, 0, 0);
        }
        #pragma unroll
        for (int d = 0; d < 4; ++d)
            part_lds[wave * 256 + (kg * 4 + d) * 16 + m] = accA[d] + accB[d];
        __syncthreads();                                    // partials ready

        // ---- cross-wave K reduction: pre_s[b][r] ----
        {
            int c2 = tid >> 8, idx = tid & 255;
            float s = part_lds[(c2 * 4 + 0) * 256 + idx] + part_lds[(c2 * 4 + 1) * 256 + idx]
                    + part_lds[(c2 * 4 + 2) * 256 + idx] + part_lds[(c2 * 4 + 3) * 256 + idx];
            pre_s[c2 * 16 + (idx & 15)][idx >> 4] = s;
        }
        __syncthreads();                                    // pre_s ready

        // ---- epilogue + publish: wave 0 only; other waves run ahead to next poll ----
        if (wave == 0) {
            int xv = x[bb * S_ + t];
            const float* Tv = T2 + (size_t)xv * G4H + (size_t)(p * 4 + u0) * 4;
            float4 ga = *(const float4*)Tv;         // gates i,f,g,o for unit u0
            float4 gb = *(const float4*)(Tv + 4);   // unit u0+1
            int r0 = u0 * 4, r1 = r0 + 4;
            float pi0 = pre_s[bb][r0+0] + ga.x + bhh_l[r0+0];
            float pf0 = pre_s[bb][r0+1] + ga.y + bhh_l[r0+1];
            float pg0 = pre_s[bb][r0+2] + ga.z + bhh_l[r0+2];
            float po0 = pre_s[bb][r0+3] + ga.w + bhh_l[r0+3];
            float pi1 = pre_s[bb][r1+0] + gb.x + bhh_l[r1+0];
            float pf1 = pre_s[bb][r1+1] + gb.y + bhh_l[r1+1];
            float pg1 = pre_s[bb][r1+2] + gb.z + bhh_l[r1+2];
            float po1 = pre_s[bb][r1+3] + gb.w + bhh_l[r1+3];
            c0 = sigf(pf0) * c0 + sigf(pi0) * tanhfast(pg0);
            c1 = sigf(pf1) * c1 + sigf(pi1) * tanhfast(pg1);
            float h0 = sigf(po0) * tanhfast(c0);
            float h1 = sigf(po1) * tanhfast(c1);

            unsigned int hp = (unsigned int)(unsigned short)f2bf(h0)
                            | ((unsigned int)(unsigned short)f2bf(h1) << 16);
            // h_all (bf16, normal cached store — visible to later kernels at dispatch end)
            *(unsigned int*)(h_all + (size_t)bb * (S_ * H_) + (size_t)t * H_ + (p * 4 + u0)) = hp;

            // exchange publish: pack 8B per batch via shfl, even lanes store
            unsigned int hq = __shfl_xor((int)hp, 1);
            if (!(lane & 1)) {
                int2 hv; hv.x = (int)hp; hv.y = (int)hq;
                gstore2_sc(hwr + bb * H_ + p * 4, hv);
            }
            asm volatile("s_waitcnt vmcnt(0)" ::: "memory");   // h_t at coherence point
            if (lane == 0) gstore1_sc(flags + p * 16, t + 1);
        }
        // NO grid barrier: flag monotonicity bounds skew; double buffer is safe.
    }
}

// ---------------- K3: expert GEMM (bf16 MFMA)  C = A . Bw^T + be ----------------
// A = h_all [32768 x 1024] bf16, Bw = We_bf [1280 x 1024] bf16, out fp32.
// 128x128 tile, BK=32, 4 waves (2x2 of 64x64), reg-staged LDS with pad.
__global__ __launch_bounds__(256) void expert_gemm(
    const ushort* __restrict__ A, const ushort* __restrict__ Bw,
    const float* __restrict__ be, float* __restrict__ out)
{
    __shared__ ushort As[128][40];   // 32 cols + 8 pad (16B-aligned rows)
    __shared__ ushort Bs[128][40];
    const int tid = threadIdx.x;
    const int bm = blockIdx.x / 10, bn = blockIdx.x % 10;
    const int m0 = bm * 128, n0 = bn * 128;
    const int lane = tid & 63, wave = tid >> 6;
    const int wm = wave >> 1, wn = wave & 1;
    const int fm = lane & 15, kg = lane >> 4;

    const int srow = tid >> 1, scol = (tid & 1) * 16;
    const ushort* Ag = A  + (size_t)(m0 + srow) * H_ + scol;
    const ushort* Bg = Bw + (size_t)(n0 + srow) * H_ + scol;

    f32x4 acc[4][4];
    #pragma unroll
    for (int i = 0; i < 4; ++i)
        #pragma unroll
        for (int j = 0; j < 4; ++j) acc[i][j] = (f32x4){0.f,0.f,0.f,0.f};

    int4 ra0 = *(const int4*)(Ag),     ra1 = *(const int4*)(Ag + 8);
    int4 rb0 = *(const int4*)(Bg),     rb1 = *(const int4*)(Bg + 8);

    for (int k0 = 0; k0 < H_; k0 += 32) {
        __syncthreads();
        *(int4*)&As[srow][scol] = ra0;  *(int4*)&As[srow][scol + 8] = ra1;
        *(int4*)&Bs[srow][scol] = rb0;  *(int4*)&Bs[srow][scol + 8] = rb1;
        __syncthreads();
        if (k0 + 32 < H_) {
            ra0 = *(const int4*)(Ag + k0 + 32);  ra1 = *(const int4*)(Ag + k0 + 40);
            rb0 = *(const int4*)(Bg + k0 + 32);  rb1 = *(const int4*)(Bg + k0 + 40);
        }
        bf16x8 af[4], bf[4];
        #pragma unroll
        for (int i = 0; i < 4; ++i) af[i] = *(const bf16x8*)&As[wm * 64 + i * 16 + fm][kg * 8];
        #pragma unroll
        for (int j = 0; j < 4; ++j) bf[j] = *(const bf16x8*)&Bs[wn * 64 + j * 16 + fm][kg * 8];
        #pragma unroll
        for (int i = 0; i < 4; ++i)
            #pragma unroll
            for (int j = 0; j < 4; ++j)
                acc[i][j] = __builtin_amdgcn_mfma_f32_16x16x32_bf16(af[i], bf[j], acc[i][j], 0, 0, 0);
    }

    const int e = bn;                       // N-tile == one expert (128 cols)
    const size_t ebase = (size_t)e * ((size_t)B_ * S_ * V_);
    #pragma unroll
    for (int i = 0; i < 4; ++i) {
        #pragma unroll
        for (int d = 0; d < 4; ++d) {
            int row = m0 + wm * 64 + i * 16 + kg * 4 + d;
            float* orow = out + ebase + (size_t)row * V_;
            #pragma unroll
            for (int j = 0; j < 4; ++j) {
                int col = wn * 64 + j * 16 + fm;
                orow[col] = acc[i][j][d] + be[n0 + col];
            }
        }
    }
}

// ---------------- K4: gating softmax (bf16 h) ----------------
__global__ __launch_bounds__(256) void gating_kernel(
    const ushort* __restrict__ h_all, const float* __restrict__ Wg,
    const float* __restrict__ bg, float* __restrict__ gate_out)
{
    int b = blockIdx.x;
    int tid = threadIdx.x;
    __shared__ float red[NE_][256];
    const ushort* h = h_all + (size_t)b * (S_ * H_) + (size_t)(S_ - 1) * H_;
    float pa[NE_];
    #pragma unroll
    for (int e = 0; e < NE_; ++e) pa[e] = 0.f;
    for (int k = tid; k < H_; k += 256) {
        float hv = bf2f(h[k]);
        #pragma unroll
        for (int e = 0; e < NE_; ++e) pa[e] += hv * Wg[e * H_ + k];
    }
    #pragma unroll
    for (int e = 0; e < NE_; ++e) red[e][tid] = pa[e];
    __syncthreads();
    for (int s = 128; s > 0; s >>= 1) {
        if (tid < s) {
            #pragma unroll
            for (int e = 0; e < NE_; ++e) red[e][tid] += red[e][tid + s];
        }
        __syncthreads();
    }
    if (tid == 0) {
        float lg[NE_], mx = -1e30f;
        #pragma unroll
        for (int e = 0; e < NE_; ++e) { lg[e] = red[e][0] + bg[e]; mx = fmaxf(mx, lg[e]); }
        float s = 0.f;
        #pragma unroll
        for (int e = 0; e < NE_; ++e) { lg[e] = expf(lg[e] - mx); s += lg[e]; }
        #pragma unroll
        for (int e = 0; e < NE_; ++e) gate_out[b * NE_ + e] = lg[e] / s;
    }
}

// ---------------- K5: combine ----------------
__global__ __launch_bounds__(256) void combine_kernel(
    const float* __restrict__ exp_out, const float* __restrict__ gate,
    float* __restrict__ comb)
{
    int idx = blockIdx.x * 256 + threadIdx.x;  // < 4194304
    int b = idx >> 17;
    float acc = 0.f;
    #pragma unroll
    for (int e = 0; e < NE_; ++e)
        acc += gate[b * NE_ + e] * exp_out[(size_t)e * (size_t)(B_ * S_ * V_) + idx];
    comb[idx] = acc;
}

extern "C" void kernel_launch(void* const* d_in, const int* in_sizes, int n_in,
                              void* d_out, int out_size, void* d_ws, size_t ws_size,
                              hipStream_t stream)
{
    const int*   x    = (const int*)  d_in[0];
    const float* emb  = (const float*)d_in[1];
    const float* W_ih = (const float*)d_in[2];
    const float* W_hh = (const float*)d_in[3];
    const float* b_ih = (const float*)d_in[4];
    const float* b_hh = (const float*)d_in[5];
    const float* We   = (const float*)d_in[6];
    const float* be   = (const float*)d_in[7];
    const float* Wg   = (const float*)d_in[8];
    const float* bg   = (const float*)d_in[9];

    float* out     = (float*)d_out;
    float* comb    = out;                               // [B,S,V]
    float* exp_out = out + 4194304;                     // [NE,B,S,V]
    float* gate    = out + 4194304 + 41943040;          // [B,NE]

    char*   ws    = (char*)d_ws;
    float*  T2    = (float*)ws;                               // 2 MB
    ushort* hbuf  = (ushort*)(ws + (2u << 20));               // 2 x 64 KB bf16
    int*    flags = (int*)   (ws + (2u << 20) + (128u << 10));// 256 x 64 B
    ushort* We_bf = (ushort*)(ws + (4u << 20));               // 2.6 MB
    ushort* h_all = (ushort*)(ws + (8u << 20));               // 67 MB [B,S,H] bf16

    // zero h double-buffer (h0 = 0) and flags — required every replay
    hipMemsetAsync(ws + (2u << 20), 0, (144u << 10), stream);

    build_T      <<<2048, 256, 0, stream>>>(emb, W_ih, b_ih, T2);
    conv_bf16    <<<(NE_ * V_ * H_ + 255) / 256, 256, 0, stream>>>(We, We_bf, NE_ * V_ * H_);
    lstm_scan    <<<256, 512, 0, stream>>>(x, T2, W_hh, b_hh, hbuf, h_all, flags);
    expert_gemm  <<<256 * 10, 256, 0, stream>>>(h_all, We_bf, be, exp_out);
    gating_kernel<<<B_, 256, 0, stream>>>(h_all, Wg, bg, gate);
    combine_kernel<<<4194304 / 256, 256, 0, stream>>>(exp_out, gate, comb);
}